// Round 9
// baseline (218.205 us; speedup 1.0000x reference)
//
#include <hip/hip_runtime.h>
#include <hip/hip_bf16.h>
#include <stdint.h>

#define N_ROWS 16384

typedef __bf16 bf16x8 __attribute__((ext_vector_type(8)));
typedef float f32x4 __attribute__((ext_vector_type(4)));

#define AS1 __attribute__((address_space(1)))
#define AS3 __attribute__((address_space(3)))

// ---------------- ws layout (bytes) ----------------
// WcS : (W_token@W_qkv)^T bf16 [384][768], 16-chunk XOR-swizzled        589824
// bc  : f32 [384]  (b_token@W_qkv + b_qkv)                                1536
// qb  : bf16 [16384][128]  (q * -log2e)                                4194304
// kb  : bf16 [16384][128]  (XOR-swizzled, staged via global_load_lds)  4194304
// wv  : f32  [16384]  ((v+bias) . W_fc)                                  65536
// part: f32  [8][16384]                                                 524288
// xb  : bf16 [16384][768]  (x pre-converted, 16-chunk XOR-swizzled)   25165824
#define OFF_WCS  0u
#define OFF_BC   589824u
#define OFF_QB   591360u
#define OFF_KB   4785664u
#define OFF_WV   8979968u
#define OFF_PART 9045504u
#define OFF_XB   9569792u

// ---- kernel 0: (a) xb = bf16(x), swizzled; (b) Wc = W_token @ W_qkv -> WcS;
//      bc = b_token @ W_qkv + b_qkv ----
// Swizzle (shared by xb, WcS, and gemm's LDS reads): within each 128-k group,
// 16-byte chunk c (= (k>>3)&15) of row r is stored at position c ^ (r&15).
// Grid: blocks [0,6144) convert x (one 8-elem chunk per thread);
//       blocks [6144,6432) do the weight prep.
__global__ void prep(const float* __restrict__ x, const float* __restrict__ Wt,
                     const float* __restrict__ Wq, const float* __restrict__ bt,
                     const float* __restrict__ bq, __bf16* __restrict__ xb,
                     __bf16* __restrict__ WcS, float* __restrict__ bc) {
    if (blockIdx.x < 6144) {
        int cid = blockIdx.x * 256 + threadIdx.x;    // [0, 16384*96)
        int r = cid / 96, cc = cid - r * 96;         // row, chunk-in-row
        int g = cc >> 4, c = cc & 15;
        const float* src = x + (size_t)r * 768 + cc * 8;
        float4 a = *(const float4*)src;
        float4 b = *(const float4*)(src + 4);
        bf16x8 o;
        o[0] = (__bf16)a.x; o[1] = (__bf16)a.y; o[2] = (__bf16)a.z; o[3] = (__bf16)a.w;
        o[4] = (__bf16)b.x; o[5] = (__bf16)b.y; o[6] = (__bf16)b.z; o[7] = (__bf16)b.w;
        *(bf16x8*)(xb + (size_t)r * 768 + g * 128 + ((c ^ (r & 15)) << 3)) = o;
        return;
    }
    int u = (blockIdx.x - 6144) * 256 + threadIdx.x;  // [0, 768*96)
    if (u < 768 * 96) {
        int k = u / 96, n4 = u % 96;
        float s[4] = {0, 0, 0, 0};
        const float* wtp = Wt + k * 128;
        const float* wqp = Wq + n4 * 4;
#pragma unroll 8
        for (int d = 0; d < 128; d++) {
            float a = wtp[d];
            float4 b = *(const float4*)(wqp + d * 384);
            s[0] += a * b.x; s[1] += a * b.y; s[2] += a * b.z; s[3] += a * b.w;
        }
        int kg = k >> 7, c = (k >> 3) & 15, k7 = k & 7;
#pragma unroll
        for (int j = 0; j < 4; j++) {
            int n = n4 * 4 + j;
            WcS[n * 768 + kg * 128 + ((c ^ (n & 15)) << 3) + k7] = (__bf16)s[j];
        }
    }
    if (u < 384) {
        float s = bq[u];
        for (int d = 0; d < 128; d++) s += bt[d] * Wq[d * 384 + u];
        bc[u] = s;
    }
}

// ---- kernel 1: qkv = xb @ Wc + bc, rebuilt for throughput ----
// BM=64, BN=128, BK=128 (6 K-steps, was 12); A is pre-converted bf16 ->
// no in-loop cvt VALU, all fragment reads are single ds_read_b128 from
// XOR-swizzled tiles (conflict-free). LDS 48 KB -> 3 blocks/CU, grid
// (256,3) = 768 = exactly 3/CU. Staging 12 x 1KB global_load_lds per
// wave per K-step (pre-swizzled sources, linear LDS dest).
__launch_bounds__(256)
__global__ void gemm_qkv(const __bf16* __restrict__ xb, const __bf16* __restrict__ WcS,
                         const float* __restrict__ bc, const float* __restrict__ W_fc,
                         __bf16* __restrict__ qb, __bf16* __restrict__ kb,
                         float* __restrict__ wv) {
    __shared__ __bf16 Asm[64 * 128];    // 16 KB
    __shared__ __bf16 Bsm[128 * 128];   // 32 KB
    __shared__ float  wred[64];
    const int tid = threadIdx.x, wave = tid >> 6, lane = tid & 63;
    const int n16 = lane & 15, q = lane >> 4;
    const int mh = wave >> 1, nw = wave & 1;
    const int row0 = blockIdx.x * 64;
    const int sp = blockIdx.y;

    // staging source pointers (swizzle pre-baked in xb/WcS; 16B per lane)
    const char* aptr[4];
    const char* bptr[8];
#pragma unroll
    for (int i = 0; i < 4; i++) {
        int ar = row0 + wave * 16 + i * 4 + (lane >> 4);
        aptr[i] = (const char*)xb + (size_t)ar * 1536 + (lane & 15) * 16;
    }
#pragma unroll
    for (int i = 0; i < 8; i++) {
        int br = sp * 128 + wave * 32 + i * 4 + (lane >> 4);
        bptr[i] = (const char*)WcS + (size_t)br * 1536 + (lane & 15) * 16;
    }

    f32x4 acc[2][4];
#pragma unroll
    for (int mt = 0; mt < 2; mt++)
#pragma unroll
        for (int t = 0; t < 4; t++) acc[mt][t] = (f32x4){0, 0, 0, 0};

    // hoisted swizzled fragment base offsets (bytes), per ks
    const char* aP = (const char*)Asm + mh * 8192 + n16 * 256;
    const char* bP = (const char*)Bsm + nw * 16384 + n16 * 256;
    int swz[4];
#pragma unroll
    for (int ks = 0; ks < 4; ks++) swz[ks] = ((ks * 4 + q) ^ n16) << 4;

    for (int kbi = 0; kbi < 6; kbi++) {
#pragma unroll
        for (int i = 0; i < 4; i++)
            __builtin_amdgcn_global_load_lds((const AS1 void*)(aptr[i] + kbi * 256),
                (AS3 void*)((char*)Asm + wave * 4096 + i * 1024), 16, 0, 0);
#pragma unroll
        for (int i = 0; i < 8; i++)
            __builtin_amdgcn_global_load_lds((const AS1 void*)(bptr[i] + kbi * 256),
                (AS3 void*)((char*)Bsm + wave * 8192 + i * 1024), 16, 0, 0);
        __syncthreads();
#pragma unroll
        for (int ks = 0; ks < 4; ks++) {
            bf16x8 af0 = *(const bf16x8*)(aP + swz[ks]);
            bf16x8 af1 = *(const bf16x8*)(aP + 4096 + swz[ks]);
#pragma unroll
            for (int t = 0; t < 4; t++) {
                bf16x8 bf = *(const bf16x8*)(bP + t * 4096 + swz[ks]);
                acc[0][t] = __builtin_amdgcn_mfma_f32_16x16x32_bf16(af0, bf, acc[0][t], 0, 0, 0);
                acc[1][t] = __builtin_amdgcn_mfma_f32_16x16x32_bf16(af1, bf, acc[1][t], 0, 0, 0);
            }
        }
        __syncthreads();
    }

    // epilogue: cols of this block = sp*128 + nw*64 + t*16 + n16
    const int clb = nw * 64 + n16;
    if (sp == 0) {
#pragma unroll
        for (int t = 0; t < 4; t++) {
            int cl = clb + t * 16;
            float bcv = bc[cl];
#pragma unroll
            for (int mt = 0; mt < 2; mt++)
#pragma unroll
                for (int r = 0; r < 4; r++) {
                    int row = row0 + mh * 32 + mt * 16 + q * 4 + r;
                    qb[row * 128 + cl] = (__bf16)((acc[mt][t][r] + bcv) * -1.44269504088896f);
                }
        }
    } else if (sp == 1) {
        // kb XOR-swizzled (16-chunk ^ row&15) for attn's staging+ds_read.
#pragma unroll
        for (int t = 0; t < 4; t++) {
            int d = clb + t * 16;
            float bcv = bc[128 + d];
#pragma unroll
            for (int mt = 0; mt < 2; mt++)
#pragma unroll
                for (int r = 0; r < 4; r++) {
                    int row = row0 + mh * 32 + mt * 16 + q * 4 + r;
                    kb[row * 128 + (((d >> 3) ^ (row & 15)) << 3) + (d & 7)] = (__bf16)(acc[mt][t][r] + bcv);
                }
        }
    } else {
        float wacc[2][4] = {{0, 0, 0, 0}, {0, 0, 0, 0}};
#pragma unroll
        for (int t = 0; t < 4; t++) {
            int cl = clb + t * 16;
            float bcv = bc[256 + cl];
            float wf = W_fc[cl];
#pragma unroll
            for (int mt = 0; mt < 2; mt++)
#pragma unroll
                for (int r = 0; r < 4; r++) wacc[mt][r] += (acc[mt][t][r] + bcv) * wf;
        }
        float vred[2][4];
#pragma unroll
        for (int mt = 0; mt < 2; mt++)
#pragma unroll
            for (int r = 0; r < 4; r++) {
                float v = wacc[mt][r];
                v += __shfl_xor(v, 1, 64);
                v += __shfl_xor(v, 2, 64);
                v += __shfl_xor(v, 4, 64);
                v += __shfl_xor(v, 8, 64);
                vred[mt][r] = v;
                if (nw == 0 && n16 == 0) wred[mh * 32 + mt * 16 + q * 4 + r] = v;
            }
        __syncthreads();
        if (nw == 1 && n16 == 0) {
#pragma unroll
            for (int mt = 0; mt < 2; mt++)
#pragma unroll
                for (int r = 0; r < 4; r++) {
                    int lr = mh * 32 + mt * 16 + q * 4 + r;
                    wv[row0 + lr] = wred[lr] + vred[mt][r];
                }
        }
    }
}

// ---- kernel 2: partial[sp][i] = sum_{j in slice sp} sigmoid(q_i.k_j) * wv_j ----
// R6 version verbatim (best measured: 91.5 us). Counted-vmcnt 4-slot ring,
// wv slice pre-staged to LDS, deferred sigmoid, setprio around MFMA.
__launch_bounds__(256, 4)
__global__ void attn(const __bf16* __restrict__ qb, const __bf16* __restrict__ kb,
                     const float* __restrict__ wv, float* __restrict__ partial) {
    __shared__ __bf16 kbuf[4 * 32 * 128];   // 32 KB ring
    __shared__ float wlds[2048];            // 8 KB: this sp's whole wv slice
    const int tid = threadIdx.x;
    const int wave = tid >> 6, lane = tid & 63;
    const int n16 = lane & 15, q = lane >> 4;
    const int bid = blockIdx.x;
    const int sp = bid & 7;                  // XCD-pinned k-slice
    const int rb = bid >> 3;                 // [0,128) row block
    const int row0 = rb * 128 + wave * 32;
    const int jb0 = sp * 2048;

    bf16x8 qf[2][4];
#pragma unroll
    for (int mt = 0; mt < 2; mt++)
#pragma unroll
        for (int ks = 0; ks < 4; ks++)
            qf[mt][ks] = *(const bf16x8*)(qb + (size_t)(row0 + mt * 16 + n16) * 128 + ks * 32 + q * 8);
    __builtin_amdgcn_sched_barrier(0);   // keep qf loads ahead of the staging queue

    // prologue staging, oldest-first: wv slice (2 loads), chunk 0 (2), chunk 1 (2)
    {
        const char* wsrc = (const char*)(wv + jb0) + tid * 16;
        char* wdst = (char*)wlds + tid * 16;
        __builtin_amdgcn_global_load_lds((const AS1 void*)wsrc, (AS3 void*)wdst, 16, 0, 0);
        __builtin_amdgcn_global_load_lds((const AS1 void*)(wsrc + 4096),
                                         (AS3 void*)(wdst + 4096), 16, 0, 0);
    }

#define ISSUE(c, slot)                                                                  \
    {                                                                                   \
        const char* gsrc = (const char*)kb + (size_t)(jb0 + (c) * 32) * 256 + wave * 2048; \
        char* gdst = (char*)kbuf + (slot) * 8192 + wave * 2048;                          \
        __builtin_amdgcn_global_load_lds((const AS1 void*)(gsrc + lane * 16),            \
                                         (AS3 void*)gdst, 16, 0, 0);                     \
        __builtin_amdgcn_global_load_lds((const AS1 void*)(gsrc + 1024 + lane * 16),     \
                                         (AS3 void*)(gdst + 1024), 16, 0, 0);            \
    }

    ISSUE(0, 0);
    ISSUE(1, 1);

    float acc[2][4] = {{0}, {0}};
    f32x4 ps0 = (f32x4){0, 0, 0, 0}, ps1 = (f32x4){0, 0, 0, 0};   // deferred scores
    float pw = 0.0f;                                               // deferred wv

    const __bf16* kaddr[4];
#pragma unroll
    for (int ks = 0; ks < 4; ks++)
        kaddr[ks] = kbuf + n16 * 128 + (((ks * 4 + q) ^ n16) << 3);
    const float* wbase = wlds + n16;

#pragma unroll 4
    for (int jc = 0; jc < 64; jc++) {
        const int jn = (jc + 2 < 64) ? jc + 2 : 63;
        ISSUE(jn, (jc + 2) & 3);

        asm volatile("s_waitcnt vmcnt(4)" ::: "memory");
        __builtin_amdgcn_sched_barrier(0);
        __builtin_amdgcn_s_barrier();

        const int slot = jc & 3;   // compile-time under unroll-4
#pragma unroll
        for (int t = 0; t < 2; t++) {
            f32x4 s0 = (f32x4){0, 0, 0, 0}, s1 = (f32x4){0, 0, 0, 0};
            __builtin_amdgcn_s_setprio(1);
#pragma unroll
            for (int ks = 0; ks < 4; ks++) {
                bf16x8 bf = *(const bf16x8*)(kaddr[ks] + slot * 4096 + t * 2048);
                s0 = __builtin_amdgcn_mfma_f32_16x16x32_bf16(qf[0][ks], bf, s0, 0, 0, 0);
                s1 = __builtin_amdgcn_mfma_f32_16x16x32_bf16(qf[1][ks], bf, s1, 0, 0, 0);
            }
            __builtin_amdgcn_s_setprio(0);
#pragma unroll
            for (int r = 0; r < 4; r++) {
                // qb pre-scaled by -log2e: sigmoid(s) = rcp(1 + exp2(s'))
                acc[0][r] += __builtin_amdgcn_rcpf(1.0f + __builtin_amdgcn_exp2f(ps0[r])) * pw;
                acc[1][r] += __builtin_amdgcn_rcpf(1.0f + __builtin_amdgcn_exp2f(ps1[r])) * pw;
            }
            ps0 = s0; ps1 = s1;
            pw = wbase[jc * 32 + t * 16];   // ds_read, broadcast per n16
        }
    }
#undef ISSUE

    // flush the last deferred t-step
#pragma unroll
    for (int r = 0; r < 4; r++) {
        acc[0][r] += __builtin_amdgcn_rcpf(1.0f + __builtin_amdgcn_exp2f(ps0[r])) * pw;
        acc[1][r] += __builtin_amdgcn_rcpf(1.0f + __builtin_amdgcn_exp2f(ps1[r])) * pw;
    }

#pragma unroll
    for (int mt = 0; mt < 2; mt++)
#pragma unroll
        for (int r = 0; r < 4; r++) {
            float v = acc[mt][r];
            v += __shfl_xor(v, 1, 64);
            v += __shfl_xor(v, 2, 64);
            v += __shfl_xor(v, 4, 64);
            v += __shfl_xor(v, 8, 64);
            if (n16 == 0) partial[sp * N_ROWS + row0 + mt * 16 + q * 4 + r] = v;
        }
}

// ---- kernel 3: deterministic reduce over 8 slices + b_fc ----
__global__ void reduce_out(const float* __restrict__ partial, const float* __restrict__ b_fc,
                           float* __restrict__ out) {
    int i = blockIdx.x * 256 + threadIdx.x;
    float v = b_fc[0];
#pragma unroll
    for (int s = 0; s < 8; s++) v += partial[s * N_ROWS + i];
    out[i] = v;
}

extern "C" void kernel_launch(void* const* d_in, const int* in_sizes, int n_in,
                              void* d_out, int out_size, void* d_ws, size_t ws_size,
                              hipStream_t stream) {
    const float* x       = (const float*)d_in[0];
    // d_in[1] = decay_value (unused by reference)
    const float* W_token = (const float*)d_in[2];
    const float* b_token = (const float*)d_in[3];
    const float* W_qkv   = (const float*)d_in[4];
    const float* b_qkv   = (const float*)d_in[5];
    const float* W_fc    = (const float*)d_in[6];
    const float* b_fc    = (const float*)d_in[7];
    float* out = (float*)d_out;
    char* ws = (char*)d_ws;

    __bf16* WcS = (__bf16*)(ws + OFF_WCS);
    float*  bc  = (float*)(ws + OFF_BC);
    __bf16* qb  = (__bf16*)(ws + OFF_QB);
    __bf16* kb  = (__bf16*)(ws + OFF_KB);
    float*  wv  = (float*)(ws + OFF_WV);
    float*  part = (float*)(ws + OFF_PART);
    __bf16* xb  = (__bf16*)(ws + OFF_XB);

    prep<<<6432, 256, 0, stream>>>(x, W_token, W_qkv, b_token, b_qkv, xb, WcS, bc);
    gemm_qkv<<<dim3(256, 3), 256, 0, stream>>>(xb, WcS, bc, W_fc, qb, kb, wv);
    attn<<<1024, 256, 0, stream>>>(qb, kb, wv, part);
    reduce_out<<<64, 256, 0, stream>>>(part, b_fc, out);
}